// Round 2
// baseline (482.266 us; speedup 1.0000x reference)
//
#include <hip/hip_runtime.h>

typedef unsigned short u16;
typedef __attribute__((ext_vector_type(8))) short short8v;
typedef __attribute__((ext_vector_type(4))) short short4v;
typedef __attribute__((ext_vector_type(4))) float float4v;
typedef __attribute__((ext_vector_type(4))) int   int4v;

#define N_NODES 8192
#define D_IN    512
#define D_OUT   128
#define SLOPEF  0.2f

static __device__ __forceinline__ float bf2f(u16 u) {
    union { unsigned int i; float f; } v; v.i = ((unsigned int)u) << 16; return v.f;
}
static __device__ __forceinline__ u16 f2bf(float f) {
    union { float f; unsigned int i; } v; v.f = f;
    unsigned int r = v.i + 0x7fff + ((v.i >> 16) & 1);
    return (u16)(r >> 16);
}
// barrier that drains LDS ops but leaves global loads (adj prefetch) in flight
static __device__ __forceinline__ void lds_barrier() {
    asm volatile("s_waitcnt lgkmcnt(0)" ::: "memory");
    __builtin_amdgcn_s_barrier();
    asm volatile("" ::: "memory");
}

// ---------------- Kernel 1: Wh = h@W (fp32 in), WhT bf16 [128][8192], f1, f2 fp32 ----------------
__global__ __launch_bounds__(256, 2) void k1_proj(
        const float* __restrict__ h, const float* __restrict__ W,
        const float* __restrict__ a, u16* __restrict__ WhT,
        float* __restrict__ f1, float* __restrict__ f2)
{
    __shared__ float hs[16 * D_IN];     // 32 KB
    __shared__ float buf[16 * 128];     // 8 KB
    __shared__ float part[16][17];
    const int tid = threadIdx.x;
    const int rowbase = blockIdx.x * 16;

    // stage h tile (fp32, 16 rows x 512 cols = 2048 float4)
    const float4v* hsrc = (const float4v*)(h + (size_t)rowbase * D_IN);
    #pragma unroll
    for (int i = 0; i < 8; i++) {
        *(float4v*)&hs[(tid + 256 * i) * 4] = hsrc[tid + 256 * i];
    }
    __syncthreads();

    const int c  = tid & 127;   // output feature
    const int rh = tid >> 7;    // row half (8 rows each)
    float acc[8];
    #pragma unroll
    for (int rr = 0; rr < 8; rr++) acc[rr] = 0.f;

    for (int k = 0; k < D_IN; k += 4) {
        float wv[4];
        #pragma unroll
        for (int kk = 0; kk < 4; kk++) wv[kk] = W[(k + kk) * D_OUT + c];
        #pragma unroll
        for (int rr = 0; rr < 8; rr++) {
            float4v hv = *(const float4v*)&hs[(rh * 8 + rr) * D_IN + k];
            acc[rr] += hv[0] * wv[0];
            acc[rr] += hv[1] * wv[1];
            acc[rr] += hv[2] * wv[2];
            acc[rr] += hv[3] * wv[3];
        }
    }

    // WhT store: feature-major bf16, 8 consecutive rows per thread -> 16B store
    {
        short8v pack;
        #pragma unroll
        for (int rr = 0; rr < 8; rr++) pack[rr] = (short)f2bf(acc[rr]);
        *(short8v*)(WhT + (size_t)c * N_NODES + rowbase + rh * 8) = pack;
    }

    const float a1 = a[c];
    const float a2 = a[D_OUT + c];

    // f1 = Wh @ a[:128]
    #pragma unroll
    for (int rr = 0; rr < 8; rr++) buf[(rh * 8 + rr) * 128 + c] = acc[rr] * a1;
    __syncthreads();
    {
        const int row = tid >> 4, seg = tid & 15;
        float p = 0.f;
        #pragma unroll
        for (int e = 0; e < 8; e++) p += buf[row * 128 + seg * 8 + e];
        part[row][seg] = p;
    }
    __syncthreads();
    if (tid < 16) {
        float s = 0.f;
        #pragma unroll
        for (int j = 0; j < 16; j++) s += part[tid][j];
        f1[rowbase + tid] = s;
    }
    __syncthreads();
    // f2 = Wh @ a[128:]
    #pragma unroll
    for (int rr = 0; rr < 8; rr++) buf[(rh * 8 + rr) * 128 + c] = acc[rr] * a2;
    __syncthreads();
    {
        const int row = tid >> 4, seg = tid & 15;
        float p = 0.f;
        #pragma unroll
        for (int e = 0; e < 8; e++) p += buf[row * 128 + seg * 8 + e];
        part[row][seg] = p;
    }
    __syncthreads();
    if (tid < 16) {
        float s = 0.f;
        #pragma unroll
        for (int j = 0; j < 16; j++) s += part[tid][j];
        f2[rowbase + tid] = s;
    }
}

// ---------------- Kernel 2: fused mask+softmax(unnormalized)+PV via MFMA ----------------
// 32 rows per block, 256-col chunks. Single pass: exp(e) is bounded (|e|<~6) so no max-sub.
__global__ __launch_bounds__(256, 1) void k2_attn(
        const int* __restrict__ adj, const u16* __restrict__ WhT,
        const float* __restrict__ f1g, const float* __restrict__ f2g,
        float* __restrict__ out)
{
    __shared__ short Pt[32 * 264];   // P tile, bf16 bits, row stride 264 (16B-aligned rows)
    __shared__ float f2s[256];
    __shared__ float f1s[32];
    __shared__ float rs[32][9];
    __shared__ float ssum[32];

    const int tid = threadIdx.x;
    const int rowbase = blockIdx.x * 32;
    const int r = tid >> 3, g = tid & 7;          // weight-phase mapping: 32 rows x 8 col-groups
    const int lane = tid & 63, w = tid >> 6;      // MFMA-phase mapping
    const int quad = lane >> 4, m16 = lane & 15;

    if (tid < 32) f1s[tid] = f1g[rowbase + tid];
    if (tid < 64) *(float4v*)&f2s[tid * 4] = *(const float4v*)&f2g[tid * 4];

    const int4v* arow = (const int4v*)(adj + (size_t)(rowbase + r) * N_NODES);
    int4v a4[8];
    #pragma unroll
    for (int i = 0; i < 8; i++) a4[i] = arow[g + 8 * i];   // chunk 0

    float4v acc[2][2];
    #pragma unroll
    for (int mt = 0; mt < 2; mt++)
        #pragma unroll
        for (int nt = 0; nt < 2; nt++) {
            acc[mt][nt][0] = 0.f; acc[mt][nt][1] = 0.f;
            acc[mt][nt][2] = 0.f; acc[mt][nt][3] = 0.f;
        }
    float lsum = 0.f;

    lds_barrier();   // f1s/f2s ready; a4 chunk-0 loads still in flight is fine (regs)

    for (int jc = 0; jc < 32; jc++) {
        // issue f2 load for NEXT chunk first (oldest in vmcnt queue -> its LDS write
        // later won't force draining the adj prefetch)
        float4v f2next;
        const bool ldf2 = (jc + 1 < 32) && (tid < 64);
        if (ldf2) f2next = *(const float4v*)&f2g[(jc + 1) * 256 + tid * 4];

        // ---- weight phase: w = adj ? exp(lrelu(f1+f2)) : 0 ----
        const float f1v = f1s[r];
        #pragma unroll
        for (int i = 0; i < 8; i++) {
            const int c0 = (g + 8 * i) * 4;
            const float4v fv = *(const float4v*)&f2s[c0];
            const int4v av = a4[i];
            short4v pv;
            #pragma unroll
            for (int e = 0; e < 4; e++) {
                float x = f1v + fv[e];
                x = fmaxf(x, SLOPEF * x);               // leaky_relu, slope<1
                const float wv = (av[e] > 0) ? __expf(x) : 0.f;
                const u16 wb = f2bf(wv);
                lsum += bf2f(wb);                        // denominator from rounded P
                pv[e] = (short)wb;
            }
            *(short4v*)&Pt[r * 264 + c0] = pv;
        }
        // prefetch next adj chunk; stays in flight across the lds_barrier
        if (jc + 1 < 32) {
            #pragma unroll
            for (int i = 0; i < 8; i++) a4[i] = arow[(jc + 1) * 64 + g + 8 * i];
        }
        lds_barrier();

        // ---- MFMA phase: acc += P[32 x 256] @ Wh[256 x 128] (this wave's 32 cols) ----
        {
            const u16* b0p = WhT + (size_t)(w * 32 + m16) * N_NODES + jc * 256 + quad * 8;
            const u16* b1p = b0p + 16 * N_NODES;
            const short* a0p = &Pt[m16 * 264 + quad * 8];
            const short* a1p = a0p + 16 * 264;
            #pragma unroll
            for (int ks = 0; ks < 8; ks++) {
                const int ko = ks * 32;
                const short8v af0 = *(const short8v*)(a0p + ko);
                const short8v af1 = *(const short8v*)(a1p + ko);
                const short8v bv0 = *(const short8v*)(b0p + ko);
                const short8v bv1 = *(const short8v*)(b1p + ko);
                acc[0][0] = __builtin_amdgcn_mfma_f32_16x16x32_bf16(af0, bv0, acc[0][0], 0, 0, 0);
                acc[0][1] = __builtin_amdgcn_mfma_f32_16x16x32_bf16(af0, bv1, acc[0][1], 0, 0, 0);
                acc[1][0] = __builtin_amdgcn_mfma_f32_16x16x32_bf16(af1, bv0, acc[1][0], 0, 0, 0);
                acc[1][1] = __builtin_amdgcn_mfma_f32_16x16x32_bf16(af1, bv1, acc[1][1], 0, 0, 0);
            }
        }
        if (ldf2) *(float4v*)&f2s[tid * 4] = f2next;
        lds_barrier();
    }

    // per-row denominator
    rs[r][g] = lsum;
    __syncthreads();
    if (tid < 32) {
        float s = 0.f;
        #pragma unroll
        for (int j = 0; j < 8; j++) s += rs[tid][j];
        ssum[tid] = s;
    }
    __syncthreads();

    // epilogue: C/D layout col=lane&15, row=quad*4+reg
    #pragma unroll
    for (int mt = 0; mt < 2; mt++) {
        #pragma unroll
        for (int nt = 0; nt < 2; nt++) {
            const int cl = w * 32 + nt * 16 + m16;
            #pragma unroll
            for (int reg = 0; reg < 4; reg++) {
                const int rl = mt * 16 + quad * 4 + reg;
                const float val = acc[mt][nt][reg] / ssum[rl];
                out[(size_t)(rowbase + rl) * D_OUT + cl] = val;
            }
        }
    }
}

extern "C" void kernel_launch(void* const* d_in, const int* in_sizes, int n_in,
                              void* d_out, int out_size, void* d_ws, size_t ws_size,
                              hipStream_t stream) {
    const float* h   = (const float*)d_in[0];
    const int*   adj = (const int*)d_in[1];
    const float* W   = (const float*)d_in[2];
    const float* a   = (const float*)d_in[3];

    u16*   WhT = (u16*)d_ws;                                   // 128*8192*2 = 2 MB
    float* f1  = (float*)((char*)d_ws + (size_t)2 * 1024 * 1024);
    float* f2  = f1 + N_NODES;

    k1_proj<<<N_NODES / 16, 256, 0, stream>>>(h, W, a, WhT, f1, f2);
    k2_attn<<<N_NODES / 32, 256, 0, stream>>>(adj, WhT, f1, f2, (float*)d_out);
}

// Round 3
// 434.129 us; speedup vs baseline: 1.1109x; 1.1109x over previous
//
#include <hip/hip_runtime.h>

typedef unsigned short u16;
typedef __attribute__((ext_vector_type(8))) short short8v;
typedef __attribute__((ext_vector_type(4))) short short4v;
typedef __attribute__((ext_vector_type(4))) float float4v;
typedef __attribute__((ext_vector_type(4))) int   int4v;

#define N_NODES 8192
#define D_IN    512
#define D_OUT   128
#define SLOPEF  0.2f
#define NSEG    4
#define SEGCOLS 2048   // N_NODES / NSEG
#define NCHUNK  8      // SEGCOLS / 256

static __device__ __forceinline__ float bf2f(u16 u) {
    union { unsigned int i; float f; } v; v.i = ((unsigned int)u) << 16; return v.f;
}
static __device__ __forceinline__ u16 f2bf(float f) {
    union { float f; unsigned int i; } v; v.f = f;
    unsigned int r = v.i + 0x7fff + ((v.i >> 16) & 1);
    return (u16)(r >> 16);
}
// barrier that drains LDS ops but leaves global loads (adj prefetch) in flight
static __device__ __forceinline__ void lds_barrier() {
    asm volatile("s_waitcnt lgkmcnt(0)" ::: "memory");
    __builtin_amdgcn_s_barrier();
    asm volatile("" ::: "memory");
}

// ---------------- Kernel 1: Wh = h@W (fp32 in), WhT bf16 [128][8192], f1, f2 fp32 ----------------
__global__ __launch_bounds__(256, 2) void k1_proj(
        const float* __restrict__ h, const float* __restrict__ W,
        const float* __restrict__ a, u16* __restrict__ WhT,
        float* __restrict__ f1, float* __restrict__ f2)
{
    __shared__ float hs[16 * D_IN];     // 32 KB
    __shared__ float buf[16 * 128];     // 8 KB
    __shared__ float part[16][17];
    const int tid = threadIdx.x;
    const int rowbase = blockIdx.x * 16;

    const float4v* hsrc = (const float4v*)(h + (size_t)rowbase * D_IN);
    #pragma unroll
    for (int i = 0; i < 8; i++) {
        *(float4v*)&hs[(tid + 256 * i) * 4] = hsrc[tid + 256 * i];
    }
    __syncthreads();

    const int c  = tid & 127;   // output feature
    const int rh = tid >> 7;    // row half (8 rows each)
    float acc[8];
    #pragma unroll
    for (int rr = 0; rr < 8; rr++) acc[rr] = 0.f;

    for (int k = 0; k < D_IN; k += 4) {
        float wv[4];
        #pragma unroll
        for (int kk = 0; kk < 4; kk++) wv[kk] = W[(k + kk) * D_OUT + c];
        #pragma unroll
        for (int rr = 0; rr < 8; rr++) {
            float4v hv = *(const float4v*)&hs[(rh * 8 + rr) * D_IN + k];
            acc[rr] += hv[0] * wv[0];
            acc[rr] += hv[1] * wv[1];
            acc[rr] += hv[2] * wv[2];
            acc[rr] += hv[3] * wv[3];
        }
    }

    {
        short8v pack;
        #pragma unroll
        for (int rr = 0; rr < 8; rr++) pack[rr] = (short)f2bf(acc[rr]);
        *(short8v*)(WhT + (size_t)c * N_NODES + rowbase + rh * 8) = pack;
    }

    const float a1 = a[c];
    const float a2 = a[D_OUT + c];

    #pragma unroll
    for (int rr = 0; rr < 8; rr++) buf[(rh * 8 + rr) * 128 + c] = acc[rr] * a1;
    __syncthreads();
    {
        const int row = tid >> 4, seg = tid & 15;
        float p = 0.f;
        #pragma unroll
        for (int e = 0; e < 8; e++) p += buf[row * 128 + seg * 8 + e];
        part[row][seg] = p;
    }
    __syncthreads();
    if (tid < 16) {
        float s = 0.f;
        #pragma unroll
        for (int j = 0; j < 16; j++) s += part[tid][j];
        f1[rowbase + tid] = s;
    }
    __syncthreads();
    #pragma unroll
    for (int rr = 0; rr < 8; rr++) buf[(rh * 8 + rr) * 128 + c] = acc[rr] * a2;
    __syncthreads();
    {
        const int row = tid >> 4, seg = tid & 15;
        float p = 0.f;
        #pragma unroll
        for (int e = 0; e < 8; e++) p += buf[row * 128 + seg * 8 + e];
        part[row][seg] = p;
    }
    __syncthreads();
    if (tid < 16) {
        float s = 0.f;
        #pragma unroll
        for (int j = 0; j < 16; j++) s += part[tid][j];
        f2[rowbase + tid] = s;
    }
}

// ---------------- Kernel 2: fused mask+exp + partial PV via MFMA (column-split) ----------------
// Block = 32 rows x 2048-col segment. Writes partial fp32 numerator + partial denominator.
__global__ __launch_bounds__(256, 4) void k2_attn(
        const int* __restrict__ adj, const u16* __restrict__ WhT,
        const float* __restrict__ f1g, const float* __restrict__ f2g,
        float* __restrict__ numw, float* __restrict__ denw)
{
    __shared__ short Pt[32 * 264];   // 16.5 KB, row stride 264 (16B-aligned rows)
    __shared__ float f2s[SEGCOLS];   // 8 KB
    __shared__ float f1s[32];
    __shared__ float rs[32][9];
    __shared__ float ssum[32];

    const int tid = threadIdx.x;
    const int rb  = blockIdx.x >> 2;        // row-block
    const int seg = blockIdx.x & 3;         // column segment
    const int rowbase = rb * 32;
    const int colbase = seg * SEGCOLS;
    const int r = tid >> 3, g = tid & 7;    // weight-phase mapping: 32 rows x 8 col-groups
    const int lane = tid & 63, w = tid >> 6;
    const int quad = lane >> 4, m16 = lane & 15;

    if (tid < 32) f1s[tid] = f1g[rowbase + tid];
    #pragma unroll
    for (int i = 0; i < 2; i++)
        *(float4v*)&f2s[(tid + 256 * i) * 4] = *(const float4v*)&f2g[colbase + (tid + 256 * i) * 4];

    const int4v* arow = (const int4v*)(adj + (size_t)(rowbase + r) * N_NODES + colbase);
    int4v a4[8];
    #pragma unroll
    for (int i = 0; i < 8; i++) a4[i] = arow[g + 8 * i];   // chunk 0

    float4v acc[2][2];
    #pragma unroll
    for (int mt = 0; mt < 2; mt++)
        #pragma unroll
        for (int nt = 0; nt < 2; nt++) {
            acc[mt][nt][0] = 0.f; acc[mt][nt][1] = 0.f;
            acc[mt][nt][2] = 0.f; acc[mt][nt][3] = 0.f;
        }
    float lsum = 0.f;

    __syncthreads();   // f1s/f2s ready

    for (int jc = 0; jc < NCHUNK; jc++) {
        // ---- weight phase: w = adj ? exp(lrelu(f1+f2)) : 0 ----
        const float f1v = f1s[r];
        #pragma unroll
        for (int i = 0; i < 8; i++) {
            const int c0 = (g + 8 * i) * 4;
            const float4v fv = *(const float4v*)&f2s[jc * 256 + c0];
            const int4v av = a4[i];
            short4v pv;
            #pragma unroll
            for (int e = 0; e < 4; e++) {
                float x = f1v + fv[e];
                x = fmaxf(x, SLOPEF * x);               // leaky_relu, slope<1
                const float wv = (av[e] > 0) ? __expf(x) : 0.f;
                const u16 wb = f2bf(wv);
                lsum += bf2f(wb);                        // denominator from rounded P
                pv[e] = (short)wb;
            }
            *(short4v*)&Pt[r * 264 + c0] = pv;
        }
        // prefetch next adj chunk; stays in flight across the lds_barrier
        if (jc + 1 < NCHUNK) {
            #pragma unroll
            for (int i = 0; i < 8; i++) a4[i] = arow[(jc + 1) * 64 + g + 8 * i];
        }
        lds_barrier();

        // ---- MFMA phase: acc += P[32 x 256] @ Wh[256 x 128] (this wave's 32 cols) ----
        {
            const u16* b0p = WhT + (size_t)(w * 32 + m16) * N_NODES + colbase + jc * 256 + quad * 8;
            const u16* b1p = b0p + 16 * N_NODES;
            const short* a0p = &Pt[m16 * 264 + quad * 8];
            const short* a1p = a0p + 16 * 264;
            #pragma unroll
            for (int ks = 0; ks < 8; ks++) {
                const int ko = ks * 32;
                const short8v af0 = *(const short8v*)(a0p + ko);
                const short8v af1 = *(const short8v*)(a1p + ko);
                const short8v bv0 = *(const short8v*)(b0p + ko);
                const short8v bv1 = *(const short8v*)(b1p + ko);
                acc[0][0] = __builtin_amdgcn_mfma_f32_16x16x32_bf16(af0, bv0, acc[0][0], 0, 0, 0);
                acc[0][1] = __builtin_amdgcn_mfma_f32_16x16x32_bf16(af0, bv1, acc[0][1], 0, 0, 0);
                acc[1][0] = __builtin_amdgcn_mfma_f32_16x16x32_bf16(af1, bv0, acc[1][0], 0, 0, 0);
                acc[1][1] = __builtin_amdgcn_mfma_f32_16x16x32_bf16(af1, bv1, acc[1][1], 0, 0, 0);
            }
        }
        lds_barrier();
    }

    // per-row partial denominator
    rs[r][g] = lsum;
    __syncthreads();
    if (tid < 32) {
        float s = 0.f;
        #pragma unroll
        for (int j = 0; j < 8; j++) s += rs[tid][j];
        ssum[tid] = s;
        denw[(size_t)(rowbase + tid) * NSEG + seg] = s;
    }
    __syncthreads();

    // epilogue: write partial numerator (undivided). C/D layout col=lane&15, row=quad*4+reg
    #pragma unroll
    for (int mt = 0; mt < 2; mt++) {
        #pragma unroll
        for (int nt = 0; nt < 2; nt++) {
            const int cl = w * 32 + nt * 16 + m16;
            #pragma unroll
            for (int reg = 0; reg < 4; reg++) {
                const int rl = mt * 16 + quad * 4 + reg;
                numw[((size_t)(rowbase + rl) * NSEG + seg) * D_OUT + cl] = acc[mt][nt][reg];
            }
        }
    }
}

// ---------------- Kernel 3: reduce partials, divide, write output ----------------
__global__ __launch_bounds__(256) void k3_reduce(
        const float* __restrict__ numw, const float* __restrict__ denw,
        float* __restrict__ out)
{
    const int tid = threadIdx.x;
    const int row = blockIdx.x * 2 + (tid >> 7);
    const int c   = tid & 127;
    float s = 0.f, d = 0.f;
    #pragma unroll
    for (int sg = 0; sg < NSEG; sg++) {
        s += numw[((size_t)row * NSEG + sg) * D_OUT + c];
        d += denw[(size_t)row * NSEG + sg];
    }
    out[(size_t)row * D_OUT + c] = s / d;
}

extern "C" void kernel_launch(void* const* d_in, const int* in_sizes, int n_in,
                              void* d_out, int out_size, void* d_ws, size_t ws_size,
                              hipStream_t stream) {
    const float* h   = (const float*)d_in[0];
    const int*   adj = (const int*)d_in[1];
    const float* W   = (const float*)d_in[2];
    const float* a   = (const float*)d_in[3];

    char* ws = (char*)d_ws;
    u16*   WhT = (u16*)ws;                                    // 2 MB
    float* f1  = (float*)(ws + (size_t)2 * 1024 * 1024);      // 32 KB
    float* f2  = f1 + N_NODES;                                // 32 KB
    float* numw = (float*)(ws + (size_t)4 * 1024 * 1024);     // 8192*4*128*4 = 16 MB
    float* denw = (float*)(ws + (size_t)20 * 1024 * 1024);    // 8192*4*4 = 128 KB

    k1_proj<<<N_NODES / 16, 256, 0, stream>>>(h, W, a, WhT, f1, f2);
    k2_attn<<<(N_NODES / 32) * NSEG, 256, 0, stream>>>(adj, WhT, f1, f2, numw, denw);
    k3_reduce<<<N_NODES / 2, 256, 0, stream>>>(numw, denw, (float*)d_out);
}